// Round 1
// baseline (325.817 us; speedup 1.0000x reference)
//
#include <hip/hip_runtime.h>

// Problem constants (from reference setup_inputs): B=8, S=2048, H=1024
#define BB 8
#define SS 2048
#define HH 1024

// ---------------------------------------------------------------------------
// Kernel 1: per-token phase. One wave (64 lanes) per token; block = 4 waves.
// Computes start/end logits (4 dots of length H), candidacy, scores.
// Emits ss[token] = start_cand ? score_s : -1e30 (same for se/end), so the
// pair kernel needs no separate boolean arrays.
// fp64 accumulation: the pair>0 / sl0<=sl1 sign thresholds are hard cutoffs;
// stay as close to the fp64 numpy reference as possible.
// ---------------------------------------------------------------------------
__global__ __launch_bounds__(256) void token_kernel(
    const float* __restrict__ rep, const int* __restrict__ mask,
    const float* __restrict__ Ws, const float* __restrict__ bs,
    const float* __restrict__ We, const float* __restrict__ be,
    const float* __restrict__ Wm, const float* __restrict__ bm,
    float* __restrict__ ss, float* __restrict__ se)
{
    const int token = blockIdx.x * 4 + (threadIdx.x >> 6);
    const int lane  = threadIdx.x & 63;
    const float* r = rep + (size_t)token * HH;

    double a0 = 0.0, a1 = 0.0, a2 = 0.0, a3 = 0.0;
    #pragma unroll
    for (int k = 0; k < HH / 256; ++k) {
        const int h = k * 256 + lane * 4;           // 4 consecutive features
        const float4 rv = *(const float4*)(r + h);
        // Ws/We are (H,2) row-major: [h][0],[h][1] interleaved
        const float4 w0 = *(const float4*)(Ws + 2 * h);      // h, h+1
        const float4 w1 = *(const float4*)(Ws + 2 * h + 4);  // h+2, h+3
        const float4 e0 = *(const float4*)(We + 2 * h);
        const float4 e1 = *(const float4*)(We + 2 * h + 4);
        a0 += (double)rv.x * w0.x + (double)rv.y * w0.z + (double)rv.z * w1.x + (double)rv.w * w1.z;
        a1 += (double)rv.x * w0.y + (double)rv.y * w0.w + (double)rv.z * w1.y + (double)rv.w * w1.w;
        a2 += (double)rv.x * e0.x + (double)rv.y * e0.z + (double)rv.z * e1.x + (double)rv.w * e1.z;
        a3 += (double)rv.x * e0.y + (double)rv.y * e0.w + (double)rv.z * e1.y + (double)rv.w * e1.w;
    }
    // wave-64 butterfly reduce (4 accumulators)
    #pragma unroll
    for (int off = 32; off >= 1; off >>= 1) {
        a0 += __shfl_down(a0, off);
        a1 += __shfl_down(a1, off);
        a2 += __shfl_down(a2, off);
        a3 += __shfl_down(a3, off);
    }
    if (lane == 0) {
        const double sl0 = a0 + (double)bs[0];
        const double sl1 = a1 + (double)bs[1];
        const double el0 = a2 + (double)be[0];
        const double el1 = a3 + (double)be[1];
        const bool m  = (mask[token] != 0);
        const bool sc = m && (sl0 <= sl1);
        const bool ec = m && (el0 <= el1);
        const double sv = sl0 * (double)Wm[0] + sl1 * (double)Wm[1];
        const double ev = el0 * (double)Wm[2] + el1 * (double)Wm[3];
        ss[token] = sc ? (float)sv : -1e30f;   // sentinel: pair>0 impossible
        se[token] = ec ? (float)ev : -1e30f;
    }
}

// ---------------------------------------------------------------------------
// Kernel 2: pair phase. Pure store-bound: 268 MB of float4 writes.
// Each thread handles 4 consecutive j for one (b,i); two 16B stores.
// grid = (S/1024, S, B), block = 256.
// ---------------------------------------------------------------------------
__global__ __launch_bounds__(256) void pair_kernel(
    const float* __restrict__ ss, const float* __restrict__ se,
    const float* __restrict__ bm,
    float* __restrict__ out_valid, float* __restrict__ out_score)
{
    const int b = blockIdx.z;
    const int i = blockIdx.y;
    const int j = (blockIdx.x * 256 + threadIdx.x) * 4;

    const float s_i = ss[b * SS + i];
    const float4 e  = *(const float4*)(se + b * SS + j);
    const float bmv = bm[0];

    // match reference add order: (score_s + score_e) + bm
    const float p0 = (s_i + e.x) + bmv;
    const float p1 = (s_i + e.y) + bmv;
    const float p2 = (s_i + e.z) + bmv;
    const float p3 = (s_i + e.w) + bmv;

    const bool v0 = (i <= j    ) && (p0 > 0.0f);
    const bool v1 = (i <= j + 1) && (p1 > 0.0f);
    const bool v2 = (i <= j + 2) && (p2 > 0.0f);
    const bool v3 = (i <= j + 3) && (p3 > 0.0f);

    const float4 vv = make_float4(v0 ? 1.0f : 0.0f, v1 ? 1.0f : 0.0f,
                                  v2 ? 1.0f : 0.0f, v3 ? 1.0f : 0.0f);
    const float4 pv = make_float4(v0 ? p0 : 0.0f, v1 ? p1 : 0.0f,
                                  v2 ? p2 : 0.0f, v3 ? p3 : 0.0f);

    const size_t off = ((size_t)b * SS + i) * SS + j;
    *(float4*)(out_valid + off) = vv;
    *(float4*)(out_score + off) = pv;
}

extern "C" void kernel_launch(void* const* d_in, const int* in_sizes, int n_in,
                              void* d_out, int out_size, void* d_ws, size_t ws_size,
                              hipStream_t stream) {
    const float* rep  = (const float*)d_in[0];
    const int*   mask = (const int*)  d_in[1];
    const float* Ws   = (const float*)d_in[2];
    const float* bs   = (const float*)d_in[3];
    const float* We   = (const float*)d_in[4];
    const float* be   = (const float*)d_in[5];
    const float* Wm   = (const float*)d_in[6];
    const float* bm   = (const float*)d_in[7];

    float* ss = (float*)d_ws;            // B*S floats
    float* se = ss + BB * SS;            // B*S floats (total 128 KB of ws)

    float* out_valid = (float*)d_out;                          // B*S*S floats
    float* out_score = out_valid + (size_t)BB * SS * SS;       // B*S*S floats

    // Phase 1: 16384 tokens, 1 wave each, 4 waves/block -> 4096 blocks
    token_kernel<<<BB * SS / 4, 256, 0, stream>>>(rep, mask, Ws, bs, We, be,
                                                  Wm, bm, ss, se);

    // Phase 2: (2, 2048, 8) blocks x 256 threads; 4 j's per thread
    dim3 g2(SS / 1024, SS, BB);
    pair_kernel<<<g2, 256, 0, stream>>>(ss, se, bm, out_valid, out_score);
}